// Round 1
// 1907.276 us; speedup vs baseline: 1.1128x; 1.1128x over previous
//
#include <hip/hip_runtime.h>
#include <math.h>

#define H   39
#define G4  156   // 4*H
#define TL  2048  // T
#define BB  512   // B

// Block layout: 320 threads (5 waves), one block per (batch, direction).
//   tid < 312 : gate-row work. row j = tid>>1 (0..155), k-half p = tid&1.
//               Lane p owns k-chunks {8m+4p .. 8m+4p+3}, m=0..4 (k=39 padded w/ 0).
//               Weights: 2 matrices x 5 float4 = 40 VGPRs -> stays in registers
//               (the previous 78-float/lane version was demoted: VGPR_Count=60).
//   tid < 39  : cell state + elementwise phase (same lanes also do row work).
__global__ __launch_bounds__(320, 5)
void lstm_bidir_kernel(const float* __restrict__ x,
                       const float* __restrict__ W_ih_f, const float* __restrict__ W_hh_f,
                       const float* __restrict__ b_ih_f, const float* __restrict__ b_hh_f,
                       const float* __restrict__ W_ih_b, const float* __restrict__ W_hh_b,
                       const float* __restrict__ b_ih_b, const float* __restrict__ b_hh_b,
                       float* __restrict__ out)
{
    const int blk = blockIdx.x;        // 0..1023
    const int b   = blk >> 1;          // batch element
    const int dir = blk & 1;           // 0 = forward, 1 = backward
    const int tid = threadIdx.x;
    const int j   = tid >> 1;          // gate row (valid for tid < 312)
    const int p   = tid & 1;           // k-half
    const bool rowActive = (tid < 2 * G4);

    const float* __restrict__ W_ih = dir ? W_ih_b : W_ih_f;
    const float* __restrict__ W_hh = dir ? W_hh_b : W_hh_f;
    const float* __restrict__ b_ih = dir ? b_ih_b : b_ih_f;
    const float* __restrict__ b_hh = dir ? b_hh_b : b_hh_f;

    __shared__ __align__(16) float xbf[40];   // x(t), padded; xbf[39] = 0
    __shared__ __align__(16) float hbf[40];   // h(t), padded; hbf[39] = 0
    __shared__ float gates[G4];
    float4* xb4 = (float4*)xbf;
    float4* hb4 = (float4*)hbf;

    // ---- load per-lane weight chunks into registers (reused 2048x) ----
    float4 wih[5], whh[5];
    float bias = 0.0f;
    if (rowActive) {
        #pragma unroll
        for (int m = 0; m < 5; ++m) {
            const int k0 = 8 * m + 4 * p;
            float a[4], h[4];
            #pragma unroll
            for (int e = 0; e < 4; ++e) {
                const int k = k0 + e;
                a[e] = (k < H) ? W_ih[j * H + k] : 0.0f;   // only k0=36 chunk pads
                h[e] = (k < H) ? W_hh[j * H + k] : 0.0f;
            }
            wih[m] = make_float4(a[0], a[1], a[2], a[3]);
            whh[m] = make_float4(h[0], h[1], h[2], h[3]);
        }
        bias = b_ih[j] + b_hh[j];
    }
    // Branchless activation: gate rows [78,117) use tanh(x) = 2*sigmoid(2x) - 1.
    const bool  isg  = (j >= 2 * H) && (j < 3 * H);
    const float amul = isg ? 2.0f : 1.0f;    // scales input AND output
    const float aoff = isg ? -1.0f : 0.0f;

    // x layout: (B, T, H) flat. out layout: (B, T, 2H) flat.
    const float* __restrict__ xrow = x + (size_t)b * (TL * H);
    float* __restrict__ orow = out + (size_t)b * (TL * 2 * H) + dir * H;

    float c = 0.0f;                    // cell state, lives in threads tid < H
    if (tid < 40) {
        hbf[tid] = 0.0f;
        const int t0 = dir ? (TL - 1) : 0;
        xbf[tid] = (tid < H) ? xrow[(size_t)t0 * H + tid] : 0.0f;
    }
    __syncthreads();

    for (int s = 0; s < TL; ++s) {
        // Prefetch next timestep's x while the dot products run.
        float xnext = 0.0f;
        if (tid < H && (s + 1) < TL) {
            const int tn = dir ? (TL - 2 - s) : (s + 1);
            xnext = xrow[(size_t)tn * H + tid];
        }

        if (rowActive) {
            float4 acc = make_float4(0.0f, 0.0f, 0.0f, 0.0f);
            #pragma unroll
            for (int m = 0; m < 5; ++m) {
                const int ci = 2 * m + p;          // float4 chunk index in LDS
                const float4 xv = xb4[ci];
                const float4 hv = hb4[ci];
                acc.x = fmaf(wih[m].x, xv.x, fmaf(whh[m].x, hv.x, acc.x));
                acc.y = fmaf(wih[m].y, xv.y, fmaf(whh[m].y, hv.y, acc.y));
                acc.z = fmaf(wih[m].z, xv.z, fmaf(whh[m].z, hv.z, acc.z));
                acc.w = fmaf(wih[m].w, xv.w, fmaf(whh[m].w, hv.w, acc.w));
            }
            float psum = (acc.x + acc.y) + (acc.z + acc.w);
            const float tot  = psum + __shfl_xor(psum, 1) + bias;
            // act = sigmoid(tot) for i/f/o rows, tanh(tot) for g rows
            const float targ = amul * tot;
            const float e    = __expf(-targ);
            const float sg   = __builtin_amdgcn_rcpf(1.0f + e);
            const float act  = fmaf(amul, sg, aoff);
            if (p == 0) gates[j] = act;
        }
        __syncthreads();   // gates ready; everyone done reading xbf/hbf

        if (tid < H) {
            const float ig = gates[tid];
            const float fg = gates[H + tid];
            const float gg = gates[2 * H + tid];
            const float og = gates[3 * H + tid];
            c = fmaf(fg, c, ig * gg);
            // tanh(c) = 2*sigmoid(2c) - 1  (saturates correctly at +-inf)
            const float e2 = __expf(-2.0f * c);
            const float th = fmaf(2.0f, __builtin_amdgcn_rcpf(1.0f + e2), -1.0f);
            const float h  = og * th;
            hbf[tid] = h;
            xbf[tid] = xnext;
            orow[(size_t)s * (2 * H) + tid] = h;   // bwd dir lands at time index s
        }
        __syncthreads();   // hbf/xbf updated before next step reads them
    }
}

extern "C" void kernel_launch(void* const* d_in, const int* in_sizes, int n_in,
                              void* d_out, int out_size, void* d_ws, size_t ws_size,
                              hipStream_t stream) {
    const float* x      = (const float*)d_in[0];
    const float* W_ih_f = (const float*)d_in[1];
    const float* W_hh_f = (const float*)d_in[2];
    const float* b_ih_f = (const float*)d_in[3];
    const float* b_hh_f = (const float*)d_in[4];
    const float* W_ih_b = (const float*)d_in[5];
    const float* W_hh_b = (const float*)d_in[6];
    const float* b_ih_b = (const float*)d_in[7];
    const float* b_hh_b = (const float*)d_in[8];
    float* out = (float*)d_out;

    dim3 grid(BB * 2);   // one block per (batch, direction)
    dim3 block(320);     // 5 waves; 312 lanes own (row, k-half) pairs
    lstm_bidir_kernel<<<grid, block, 0, stream>>>(
        x, W_ih_f, W_hh_f, b_ih_f, b_hh_f,
        W_ih_b, W_hh_b, b_ih_b, b_hh_b, out);
}